// Round 3
// baseline (137.744 us; speedup 1.0000x reference)
//
#include <hip/hip_runtime.h>
#include <hip/hip_bf16.h>

// SelfAttention b=2, heads=8, D=32, n=4096.
// Pass 1 (proj_kernel): x -> Q,K (bf16 [bg][n][32]) and V^T (bf16 [bg][32][n]).
//                       Q pre-scaled by SCALE*log2(e).
// Pass 2 (attn_kernel): MFMA flash attention, 4 indep waves/block, 32 q/wave.
//   QK^T + PV + Wp-projection all via mfma_f32_16x16x32_bf16.
//   No max-subtraction (logits bounded); P/O transposed via per-wave
//   XOR-swizzled LDS tile; no barriers.

constexpr int D = 32;
constexpr int N = 4096;
constexpr int NBG = 16;
constexpr float SCALE = 0.17677669529663687f;   // 32^-0.5
constexpr float LOG2E = 1.4426950408889634f;

using bfrag = __attribute__((ext_vector_type(8))) short;   // 8 bf16
using f32x4 = __attribute__((ext_vector_type(4))) float;
typedef unsigned short u16;
typedef unsigned int u32;

__device__ __forceinline__ u16 f2bf(float f) {
    __hip_bfloat16 h = __float2bfloat16(f);
    return __builtin_bit_cast(u16, h);
}
__device__ __forceinline__ float fexp2(float x) { return __builtin_amdgcn_exp2f(x); }

// ---------------- pass 1: projections -> bf16 scratch ----------------
__global__ __launch_bounds__(256) void proj_kernel(
    const float* __restrict__ x,
    const float* __restrict__ Wq, const float* __restrict__ bq,
    const float* __restrict__ Wk, const float* __restrict__ bk,
    const float* __restrict__ Wv, const float* __restrict__ bv,
    u16* __restrict__ Qb, u16* __restrict__ Kb, u16* __restrict__ VT) {
    const int bg = blockIdx.y, g = bg & 7;
    const int i = blockIdx.x * 256 + threadIdx.x;

    const float* xb = x + (size_t)bg * D * N;
    float xv[D];
#pragma unroll
    for (int d = 0; d < D; ++d) xv[d] = xb[(size_t)d * N + i];

    const float* wq = Wq + g * D * D;
    const float* wk = Wk + g * D * D;
    const float* wv = Wv + g * D * D;

    u16 qh[D], kh[D];
#pragma unroll
    for (int o = 0; o < D; ++o) {
        float q0 = 0.f, q1 = 0.f, k0 = 0.f, k1 = 0.f, v0 = 0.f, v1 = 0.f;
#pragma unroll
        for (int d = 0; d < D; d += 2) {
            q0 = fmaf(wq[o * D + d    ], xv[d    ], q0);
            q1 = fmaf(wq[o * D + d + 1], xv[d + 1], q1);
            k0 = fmaf(wk[o * D + d    ], xv[d    ], k0);
            k1 = fmaf(wk[o * D + d + 1], xv[d + 1], k1);
            v0 = fmaf(wv[o * D + d    ], xv[d    ], v0);
            v1 = fmaf(wv[o * D + d + 1], xv[d + 1], v1);
        }
        qh[o] = f2bf((q0 + q1 + bq[g * D + o]) * (SCALE * LOG2E));
        kh[o] = f2bf(k0 + k1 + bk[g * D + o]);
        VT[(size_t)bg * D * N + (size_t)o * N + i] = f2bf(v0 + v1 + bv[g * D + o]);
    }

    u16* Qp = Qb + ((size_t)bg * N + i) * D;
    u16* Kp = Kb + ((size_t)bg * N + i) * D;
#pragma unroll
    for (int t = 0; t < 4; ++t) {
        u32 a0 = (u32)qh[8 * t    ] | ((u32)qh[8 * t + 1] << 16);
        u32 a1 = (u32)qh[8 * t + 2] | ((u32)qh[8 * t + 3] << 16);
        u32 a2 = (u32)qh[8 * t + 4] | ((u32)qh[8 * t + 5] << 16);
        u32 a3 = (u32)qh[8 * t + 6] | ((u32)qh[8 * t + 7] << 16);
        *reinterpret_cast<uint4*>(Qp + 8 * t) = make_uint4(a0, a1, a2, a3);
        u32 b0 = (u32)kh[8 * t    ] | ((u32)kh[8 * t + 1] << 16);
        u32 b1 = (u32)kh[8 * t + 2] | ((u32)kh[8 * t + 3] << 16);
        u32 b2 = (u32)kh[8 * t + 4] | ((u32)kh[8 * t + 5] << 16);
        u32 b3 = (u32)kh[8 * t + 6] | ((u32)kh[8 * t + 7] << 16);
        *reinterpret_cast<uint4*>(Kp + 8 * t) = make_uint4(b0, b1, b2, b3);
    }
}

// ---------------- pass 2: MFMA flash attention ----------------
__global__ __launch_bounds__(256) void attn_kernel(
    const u16* __restrict__ Qb, const u16* __restrict__ Kb, const u16* __restrict__ VT,
    const float* __restrict__ Wp, const float* __restrict__ bp,
    float* __restrict__ out) {
    const int s = blockIdx.x;
    const int bg = s & 15, qt = s >> 4, g = bg & 7;   // bg fastest -> same-bg blocks share XCD L2
    const int wid = threadIdx.x >> 6;
    const int lane = threadIdx.x & 63;
    const int l15 = lane & 15, grp = lane >> 4;
    const int qbase = qt * 128 + wid * 32;            // 32 q rows per wave

    // per-wave LDS transpose tile, stride 40 u16 (80 B) + XOR swizzle
    __shared__ u16 plds_all[4][32][40];
    u16 (*plds)[40] = plds_all[wid];

    // swizzled column indices (constant per lane)
    const int colw0 = l15        ^ (grp << 3);       // for key/d sub-chunk 0 writes
    const int colw1 = (16 + l15) ^ (grp << 3);       // for key/d sub-chunk 1 writes
    const int colr  = (grp ^ (l15 >> 2)) * 8;        // fragment-read column base

    const u16* Qw = Qb + (size_t)bg * N * D;
    const u16* Kw = Kb + (size_t)bg * N * D;
    const u16* Vw = VT + (size_t)bg * D * N;

    // Q A-fragments (held whole loop)
    bfrag qf[2];
#pragma unroll
    for (int qg = 0; qg < 2; ++qg)
        qf[qg] = *reinterpret_cast<const bfrag*>(Qw + (size_t)(qbase + qg * 16 + l15) * D + grp * 8);

    // Wp B-fragments + bias (loaded once, fp32 -> bf16 in-reg)
    bfrag wf[2];
    float bias[2];
#pragma unroll
    for (int oh = 0; oh < 2; ++oh) {
        const float* wrow = Wp + (size_t)(g * D + oh * 16 + l15) * D + grp * 8;
        bfrag w;
#pragma unroll
        for (int e = 0; e < 8; ++e) w[e] = (short)f2bf(wrow[e]);
        wf[oh] = w;
        bias[oh] = bp[g * D + oh * 16 + l15];
    }

    const f32x4 zf = {0.f, 0.f, 0.f, 0.f};
    f32x4 oacc[2][2];      // [qgroup][d-half]
    f32x4 lp[2];           // softmax denominators, rows = grp*4+r
#pragma unroll
    for (int qg = 0; qg < 2; ++qg) {
        lp[qg] = zf;
        oacc[qg][0] = zf;
        oacc[qg][1] = zf;
    }

    for (int kb = 0; kb < N; kb += 32) {
        // K B-frags (col=key), V B-frags (col=d) -- direct global, coalesced
        bfrag kf0 = *reinterpret_cast<const bfrag*>(Kw + (size_t)(kb + l15) * D + grp * 8);
        bfrag kf1 = *reinterpret_cast<const bfrag*>(Kw + (size_t)(kb + 16 + l15) * D + grp * 8);
        bfrag vf0 = *reinterpret_cast<const bfrag*>(Vw + (size_t)l15 * N + kb + grp * 8);
        bfrag vf1 = *reinterpret_cast<const bfrag*>(Vw + (size_t)(16 + l15) * N + kb + grp * 8);

        f32x4 sf[2][2];
#pragma unroll
        for (int qg = 0; qg < 2; ++qg) {
            sf[qg][0] = __builtin_amdgcn_mfma_f32_16x16x32_bf16(qf[qg], kf0, zf, 0, 0, 0);
            sf[qg][1] = __builtin_amdgcn_mfma_f32_16x16x32_bf16(qf[qg], kf1, zf, 0, 0, 0);
        }

        // exp2, accumulate denominator, write P (bf16) to swizzled LDS
#pragma unroll
        for (int qg = 0; qg < 2; ++qg) {
#pragma unroll
            for (int r = 0; r < 4; ++r) {
                float e0 = fexp2(sf[qg][0][r]);
                float e1 = fexp2(sf[qg][1][r]);
                lp[qg][r] += e0 + e1;
                const int row = qg * 16 + grp * 4 + r;
                plds[row][colw0] = f2bf(e0);
                plds[row][colw1] = f2bf(e1);
            }
        }

        // read P as A-fragments (per-wave LDS; compiler orders via lgkmcnt)
        bfrag pf0 = *reinterpret_cast<const bfrag*>(&plds[l15][colr]);
        bfrag pf1 = *reinterpret_cast<const bfrag*>(&plds[16 + l15][colr]);

#pragma unroll
        for (int dh = 0; dh < 2; ++dh) {
            oacc[0][dh] = __builtin_amdgcn_mfma_f32_16x16x32_bf16(pf0, dh ? vf1 : vf0, oacc[0][dh], 0, 0, 0);
            oacc[1][dh] = __builtin_amdgcn_mfma_f32_16x16x32_bf16(pf1, dh ? vf1 : vf0, oacc[1][dh], 0, 0, 0);
        }
    }

    // denominator: reduce across the 16 col-lanes, invert
#pragma unroll
    for (int qg = 0; qg < 2; ++qg) {
#pragma unroll
        for (int r = 0; r < 4; ++r) {
            float v = lp[qg][r];
            v += __shfl_xor(v, 1);
            v += __shfl_xor(v, 2);
            v += __shfl_xor(v, 4);
            v += __shfl_xor(v, 8);
            lp[qg][r] = 1.0f / v;
        }
    }

    // normalize O, transpose via LDS (same swizzle) for the Wp MFMA
#pragma unroll
    for (int qg = 0; qg < 2; ++qg) {
#pragma unroll
        for (int dh = 0; dh < 2; ++dh) {
#pragma unroll
            for (int r = 0; r < 4; ++r) {
                const int row = qg * 16 + grp * 4 + r;
                plds[row][dh ? colw1 : colw0] = f2bf(oacc[qg][dh][r] * lp[qg][r]);
            }
        }
    }
    bfrag of0 = *reinterpret_cast<const bfrag*>(&plds[l15][colr]);
    bfrag of1 = *reinterpret_cast<const bfrag*>(&plds[16 + l15][colr]);

    // out[o][q] = Wp @ O + bp, stored as float4 along q
#pragma unroll
    for (int qg = 0; qg < 2; ++qg) {
#pragma unroll
        for (int oh = 0; oh < 2; ++oh) {
            f32x4 c = {bias[oh], bias[oh], bias[oh], bias[oh]};
            c = __builtin_amdgcn_mfma_f32_16x16x32_bf16(qg ? of1 : of0, wf[oh], c, 0, 0, 0);
            float4 st = make_float4(c[0], c[1], c[2], c[3]);
            *reinterpret_cast<float4*>(out + (size_t)bg * D * N +
                                       (size_t)(oh * 16 + l15) * N +
                                       qbase + qg * 16 + grp * 4) = st;
        }
    }
}

extern "C" void kernel_launch(void* const* d_in, const int* in_sizes, int n_in,
                              void* d_out, int out_size, void* d_ws, size_t ws_size,
                              hipStream_t stream) {
    const float* x  = (const float*)d_in[0];
    const float* Wq = (const float*)d_in[1];
    const float* bq = (const float*)d_in[2];
    const float* Wk = (const float*)d_in[3];
    const float* bk = (const float*)d_in[4];
    const float* Wv = (const float*)d_in[5];
    const float* bv = (const float*)d_in[6];
    const float* Wp = (const float*)d_in[7];
    const float* bp = (const float*)d_in[8];
    float* out = (float*)d_out;

    u16* Qb = (u16*)d_ws;                        // [16][4096][32] bf16 = 4 MB
    u16* Kb = Qb + (size_t)NBG * N * D;          // 4 MB
    u16* VT = Kb + (size_t)NBG * N * D;          // [16][32][4096] bf16 = 4 MB

    proj_kernel<<<dim3(N / 256, NBG), 256, 0, stream>>>(x, Wq, bq, Wk, bk, Wv, bv, Qb, Kb, VT);
    attn_kernel<<<dim3(NBG * (N / 128)), 256, 0, stream>>>(Qb, Kb, VT, Wp, bp, out);
}

// Round 5
// 107.746 us; speedup vs baseline: 1.2784x; 1.2784x over previous
//
#include <hip/hip_runtime.h>
#include <hip/hip_bf16.h>

// SelfAttention b=2, heads=8, D=32, n=4096 (64x64).
// Pass 1 (proj_kernel, z=Q/K/V): x -> Q,K bf16 [bg][n][32] (Q pre-scaled by
//   SCALE*log2e), V^T bf16 [bg][32][n].
// Pass 2 (attn_kernel): MFMA flash attention, 4 indep waves/block, 32 q/wave.
//   Swapped QK^T (mfma(K,Q) -> S^T) so 4 adjacent keys are lane-local:
//   exp2 -> packed short4 ds_write_b64. P/O tiles in per-wave LDS, stride
//   80B (bank-uniform). No block barriers. K/V register-prefetched.
// LDS accesses are all short-element typed + explicit compiler memory
// barriers between write->read handoffs (TBAA reorder bug fix, round 3).

constexpr int D = 32;
constexpr int N = 4096;
constexpr int NBG = 16;
constexpr float SCALE = 0.17677669529663687f;   // 32^-0.5
constexpr float LOG2E = 1.4426950408889634f;

using bfrag = __attribute__((ext_vector_type(8))) short;   // 8 bf16
using s16x4 = __attribute__((ext_vector_type(4))) short;
using s16x8 = __attribute__((ext_vector_type(8))) short;
using f32x4 = __attribute__((ext_vector_type(4))) float;
typedef unsigned short u16;
typedef unsigned int u32;

__device__ __forceinline__ float fexp2(float x) { return __builtin_amdgcn_exp2f(x); }

__device__ __forceinline__ short f2bfs(float f) {
    __hip_bfloat16 h = __float2bfloat16(f);
    return (short)__builtin_bit_cast(u16, h);
}

// ---------------- pass 1: projections -> bf16 scratch ----------------
__global__ __launch_bounds__(256) void proj_kernel(
    const float* __restrict__ x,
    const float* __restrict__ Wq, const float* __restrict__ bq,
    const float* __restrict__ Wk, const float* __restrict__ bk,
    const float* __restrict__ Wv, const float* __restrict__ bv,
    u16* __restrict__ Qb, u16* __restrict__ Kb, u16* __restrict__ VT) {
    const int bg = blockIdx.y, g = bg & 7;
    const int z  = blockIdx.z;                       // 0=Q 1=K 2=V
    const int i  = blockIdx.x * 256 + threadIdx.x;

    const float* W  = (z == 0) ? Wq : (z == 1) ? Wk : Wv;
    const float* bb = (z == 0) ? bq : (z == 1) ? bk : bv;

    const float* xb = x + (size_t)bg * D * N;
    float xv[D];
#pragma unroll
    for (int d = 0; d < D; ++d) xv[d] = xb[(size_t)d * N + i];

    const float* w = W + g * D * D;
    float acc[D];
#pragma unroll
    for (int o = 0; o < D; ++o) {
        float a0 = 0.f, a1 = 0.f, a2 = 0.f, a3 = 0.f;
#pragma unroll
        for (int d = 0; d < D; d += 4) {
            a0 = fmaf(w[o * D + d    ], xv[d    ], a0);
            a1 = fmaf(w[o * D + d + 1], xv[d + 1], a1);
            a2 = fmaf(w[o * D + d + 2], xv[d + 2], a2);
            a3 = fmaf(w[o * D + d + 3], xv[d + 3], a3);
        }
        acc[o] = (a0 + a1) + (a2 + a3) + bb[g * D + o];
    }

    if (z == 2) {                                    // V -> transposed [d][n]
        u16* vp = VT + (size_t)bg * D * N + i;
#pragma unroll
        for (int o = 0; o < D; ++o)
            vp[(size_t)o * N] = (u16)f2bfs(acc[o]);
    } else {                                         // Q/K -> row [n][32]
        const float s = (z == 0) ? (SCALE * LOG2E) : 1.0f;
        u16* dst = ((z == 0) ? Qb : Kb) + ((size_t)bg * N + i) * D;
#pragma unroll
        for (int t = 0; t < 4; ++t) {
            s16x8 v;
#pragma unroll
            for (int e = 0; e < 8; ++e) v[e] = f2bfs(acc[8 * t + e] * s);
            *reinterpret_cast<s16x8*>(dst + 8 * t) = v;
        }
    }
}

// ---------------- pass 2: MFMA flash attention ----------------
__global__ __launch_bounds__(256) void attn_kernel(
    const u16* __restrict__ Qb, const u16* __restrict__ Kb, const u16* __restrict__ VT,
    const float* __restrict__ Wp, const float* __restrict__ bp,
    float* __restrict__ out) {
    const int s = blockIdx.x;
    const int bg = s & 15, qt = s >> 4, g = bg & 7;   // bg fastest -> XCD L2 reuse
    const int wid = threadIdx.x >> 6;
    const int lane = threadIdx.x & 63;
    const int l15 = lane & 15, grp = lane >> 4;
    const int qbase = qt * 128 + wid * 32;            // 32 q rows per wave

    // per-wave P/O tile: [2 qg][16 rows][40 u16] (80B stride, bank-uniform)
    __shared__ u16 plds_all[4][2][16][40];
    u16* base = &plds_all[wid][0][0][0];
    u16* pw = base + l15 * 40 + grp * 4;              // P write base (row=q=l15)
    const u16* pr = base + l15 * 40 + grp * 8;        // A-frag read base

    const u16* Qw = Qb + (size_t)bg * N * D;
    const u16* Kw = Kb + (size_t)bg * N * D;
    const u16* Vw = VT + (size_t)bg * D * N;

    // Q B-fragments (held whole loop): col=q, k=d
    bfrag qf[2];
#pragma unroll
    for (int qg = 0; qg < 2; ++qg)
        qf[qg] = *reinterpret_cast<const bfrag*>(Qw + (size_t)(qbase + qg * 16 + l15) * D + grp * 8);

    // Wp B-fragments + bias (scalar converts; compiler fuses to cvt_pk)
    bfrag wf[2];
    float bias[2];
#pragma unroll
    for (int oh = 0; oh < 2; ++oh) {
        const float* wrow = Wp + (size_t)(g * D + oh * 16 + l15) * D + grp * 8;
        bfrag w;
#pragma unroll
        for (int e = 0; e < 8; ++e) w[e] = f2bfs(wrow[e]);
        wf[oh] = w;
        bias[oh] = bp[g * D + oh * 16 + l15];
    }

    const f32x4 zf = {0.f, 0.f, 0.f, 0.f};
    f32x4 oacc[2][2];       // [qg][d-half], D[q][d]: row=q, col=d
    float lacc[2] = {0.f, 0.f};
#pragma unroll
    for (int qg = 0; qg < 2; ++qg) { oacc[qg][0] = zf; oacc[qg][1] = zf; }

    const u16* kA = Kw + (size_t)l15 * D + grp * 8;
    const u16* kB = kA + 16 * D;
    const u16* vA = Vw + (size_t)l15 * N + grp * 8;
    const u16* vB = vA + 16 * N;

    bfrag kf0 = *reinterpret_cast<const bfrag*>(kA);
    bfrag kf1 = *reinterpret_cast<const bfrag*>(kB);
    bfrag vf0 = *reinterpret_cast<const bfrag*>(vA);
    bfrag vf1 = *reinterpret_cast<const bfrag*>(vB);

    for (int kb = 0; kb < N; kb += 32) {
        bfrag k0c = kf0, k1c = kf1, v0c = vf0, v1c = vf1;
        if (kb + 32 < N) {                            // register prefetch
            kf0 = *reinterpret_cast<const bfrag*>(kA + (size_t)(kb + 32) * D);
            kf1 = *reinterpret_cast<const bfrag*>(kB + (size_t)(kb + 32) * D);
            vf0 = *reinterpret_cast<const bfrag*>(vA + kb + 32);
            vf1 = *reinterpret_cast<const bfrag*>(vB + kb + 32);
        }

        // S^T = mfma(K, Q): lane holds 4 adjacent keys (rows) for q=l15 (col)
#pragma unroll
        for (int qg = 0; qg < 2; ++qg) {
            f32x4 s0 = __builtin_amdgcn_mfma_f32_16x16x32_bf16(k0c, qf[qg], zf, 0, 0, 0);
            f32x4 s1 = __builtin_amdgcn_mfma_f32_16x16x32_bf16(k1c, qf[qg], zf, 0, 0, 0);
            float e0 = fexp2(s0[0]), e1 = fexp2(s0[1]), e2 = fexp2(s0[2]), e3 = fexp2(s0[3]);
            float e4 = fexp2(s1[0]), e5 = fexp2(s1[1]), e6 = fexp2(s1[2]), e7 = fexp2(s1[3]);
            lacc[qg] += ((e0 + e1) + (e2 + e3)) + ((e4 + e5) + (e6 + e7));
            // keys grp*4+{0..3} and 16+grp*4+{0..3} -> two b64 at row q=l15
            s16x4 w0 = { f2bfs(e0), f2bfs(e1), f2bfs(e2), f2bfs(e3) };
            s16x4 w1 = { f2bfs(e4), f2bfs(e5), f2bfs(e6), f2bfs(e7) };
            *reinterpret_cast<s16x4*>(pw + qg * 640)      = w0;
            *reinterpret_cast<s16x4*>(pw + qg * 640 + 16) = w1;
        }

        // order: all P writes BEFORE the fragment reads
        asm volatile("" ::: "memory");

        // P A-fragments (row=q=l15, k=keys grp*8..+7)
        bfrag pf0 = *reinterpret_cast<const bfrag*>(pr);
        bfrag pf1 = *reinterpret_cast<const bfrag*>(pr + 640);

        // order: reads BEFORE next iteration's writes
        asm volatile("" ::: "memory");

#pragma unroll
        for (int dh = 0; dh < 2; ++dh) {
            oacc[0][dh] = __builtin_amdgcn_mfma_f32_16x16x32_bf16(pf0, dh ? v1c : v0c, oacc[0][dh], 0, 0, 0);
            oacc[1][dh] = __builtin_amdgcn_mfma_f32_16x16x32_bf16(pf1, dh ? v1c : v0c, oacc[1][dh], 0, 0, 0);
        }
    }

    // denominators: lane-local partial, reduce over grp (lanes ^16, ^32)
    float linv[2];
#pragma unroll
    for (int qg = 0; qg < 2; ++qg) {
        float v = lacc[qg];
        v += __shfl_xor(v, 16);
        v += __shfl_xor(v, 32);
        linv[qg] = 1.0f / v;
    }

    // normalize O (rows q=grp*4+r need linv from lane q) and write O tile
#pragma unroll
    for (int qg = 0; qg < 2; ++qg) {
#pragma unroll
        for (int r = 0; r < 4; ++r) {
            const float ir = __shfl(linv[qg], grp * 4 + r);
            u16* po = base + qg * 640 + (grp * 4 + r) * 40 + l15;
#pragma unroll
            for (int dh = 0; dh < 2; ++dh)
                po[dh * 16] = (u16)f2bfs(oacc[qg][dh][r] * ir);
        }
    }

    asm volatile("" ::: "memory");

    bfrag of0 = *reinterpret_cast<const bfrag*>(pr);
    bfrag of1 = *reinterpret_cast<const bfrag*>(pr + 640);

    // out[o][q] = Wp @ O + bp
#pragma unroll
    for (int qg = 0; qg < 2; ++qg) {
#pragma unroll
        for (int oh = 0; oh < 2; ++oh) {
            f32x4 c = {bias[oh], bias[oh], bias[oh], bias[oh]};
            c = __builtin_amdgcn_mfma_f32_16x16x32_bf16(qg ? of1 : of0, wf[oh], c, 0, 0, 0);
            *reinterpret_cast<float4*>(out + (size_t)bg * D * N +
                                       (size_t)(oh * 16 + l15) * N +
                                       qbase + qg * 16 + grp * 4) =
                make_float4(c[0], c[1], c[2], c[3]);
        }
    }
}

extern "C" void kernel_launch(void* const* d_in, const int* in_sizes, int n_in,
                              void* d_out, int out_size, void* d_ws, size_t ws_size,
                              hipStream_t stream) {
    const float* x  = (const float*)d_in[0];
    const float* Wq = (const float*)d_in[1];
    const float* bq = (const float*)d_in[2];
    const float* Wk = (const float*)d_in[3];
    const float* bk = (const float*)d_in[4];
    const float* Wv = (const float*)d_in[5];
    const float* bv = (const float*)d_in[6];
    const float* Wp = (const float*)d_in[7];
    const float* bp = (const float*)d_in[8];
    float* out = (float*)d_out;

    u16* Qb = (u16*)d_ws;                        // [16][4096][32] bf16 = 4 MB
    u16* Kb = Qb + (size_t)NBG * N * D;          // 4 MB
    u16* VT = Kb + (size_t)NBG * N * D;          // [16][32][4096] bf16 = 4 MB

    proj_kernel<<<dim3(N / 256, NBG, 3), 256, 0, stream>>>(x, Wq, bq, Wk, bk, Wv, bv, Qb, Kb, VT);
    attn_kernel<<<dim3(NBG * (N / 128)), 256, 0, stream>>>(Qb, Kb, VT, Wp, bp, out);
}

// Round 6
// 107.471 us; speedup vs baseline: 1.2817x; 1.0026x over previous
//
#include <hip/hip_runtime.h>
#include <hip/hip_bf16.h>

// SelfAttention b=2, heads=8, D=32, n=4096 (64x64).
// Pass 1 (proj_kernel, z=Q/K/V): x -> Q,K bf16 [bg][n][32] (Q pre-scaled by
//   SCALE*log2e), V^T bf16 [bg][32][n].
// Pass 2 (attn_kernel): MFMA flash attention, 4 indep waves/block, 32 q/wave.
//   Swapped QK^T (mfma(K,Q) -> S^T) so 4 adjacent keys are lane-local:
//   exp2 -> packed short4 ds_write_b64. P/O tiles in per-wave LDS, stride
//   80B (bank-uniform). No block barriers. K/V register-prefetched.
// LDS accesses are all short-element typed + explicit compiler memory
// barriers between write->read handoffs (TBAA reorder bug fix, round 3).

constexpr int D = 32;
constexpr int N = 4096;
constexpr int NBG = 16;
constexpr float SCALE = 0.17677669529663687f;   // 32^-0.5
constexpr float LOG2E = 1.4426950408889634f;

using bfrag = __attribute__((ext_vector_type(8))) short;   // 8 bf16
using s16x4 = __attribute__((ext_vector_type(4))) short;
using s16x8 = __attribute__((ext_vector_type(8))) short;
using f32x4 = __attribute__((ext_vector_type(4))) float;
typedef unsigned short u16;
typedef unsigned int u32;

__device__ __forceinline__ float fexp2(float x) { return __builtin_amdgcn_exp2f(x); }

__device__ __forceinline__ short f2bfs(float f) {
    __hip_bfloat16 h = __float2bfloat16(f);
    return (short)__builtin_bit_cast(u16, h);
}

// ---------------- pass 1: projections -> bf16 scratch ----------------
__global__ __launch_bounds__(256) void proj_kernel(
    const float* __restrict__ x,
    const float* __restrict__ Wq, const float* __restrict__ bq,
    const float* __restrict__ Wk, const float* __restrict__ bk,
    const float* __restrict__ Wv, const float* __restrict__ bv,
    u16* __restrict__ Qb, u16* __restrict__ Kb, u16* __restrict__ VT) {
    const int bg = blockIdx.y, g = bg & 7;
    const int z  = blockIdx.z;                       // 0=Q 1=K 2=V
    const int i  = blockIdx.x * 256 + threadIdx.x;

    const float* W  = (z == 0) ? Wq : (z == 1) ? Wk : Wv;
    const float* bb = (z == 0) ? bq : (z == 1) ? bk : bv;

    const float* xb = x + (size_t)bg * D * N;
    float xv[D];
#pragma unroll
    for (int d = 0; d < D; ++d) xv[d] = xb[(size_t)d * N + i];

    const float* w = W + g * D * D;
    float acc[D];
#pragma unroll
    for (int o = 0; o < D; ++o) {
        float a0 = 0.f, a1 = 0.f, a2 = 0.f, a3 = 0.f;
#pragma unroll
        for (int d = 0; d < D; d += 4) {
            a0 = fmaf(w[o * D + d    ], xv[d    ], a0);
            a1 = fmaf(w[o * D + d + 1], xv[d + 1], a1);
            a2 = fmaf(w[o * D + d + 2], xv[d + 2], a2);
            a3 = fmaf(w[o * D + d + 3], xv[d + 3], a3);
        }
        acc[o] = (a0 + a1) + (a2 + a3) + bb[g * D + o];
    }

    if (z == 2) {                                    // V -> transposed [d][n]
        u16* vp = VT + (size_t)bg * D * N + i;
#pragma unroll
        for (int o = 0; o < D; ++o)
            vp[(size_t)o * N] = (u16)f2bfs(acc[o]);
    } else {                                         // Q/K -> row [n][32]
        const float s = (z == 0) ? (SCALE * LOG2E) : 1.0f;
        u16* dst = ((z == 0) ? Qb : Kb) + ((size_t)bg * N + i) * D;
#pragma unroll
        for (int t = 0; t < 4; ++t) {
            s16x8 v;
#pragma unroll
            for (int e = 0; e < 8; ++e) v[e] = f2bfs(acc[8 * t + e] * s);
            *reinterpret_cast<s16x8*>(dst + 8 * t) = v;
        }
    }
}

// ---------------- pass 2: MFMA flash attention ----------------
__global__ __launch_bounds__(256) void attn_kernel(
    const u16* __restrict__ Qb, const u16* __restrict__ Kb, const u16* __restrict__ VT,
    const float* __restrict__ Wp, const float* __restrict__ bp,
    float* __restrict__ out) {
    const int s = blockIdx.x;
    const int bg = s & 15, qt = s >> 4, g = bg & 7;   // bg fastest -> XCD L2 reuse
    const int wid = threadIdx.x >> 6;
    const int lane = threadIdx.x & 63;
    const int l15 = lane & 15, grp = lane >> 4;
    const int qbase = qt * 128 + wid * 32;            // 32 q rows per wave

    // per-wave P/O tile: [2 qg][16 rows][40 u16] (80B stride, bank-uniform)
    __shared__ u16 plds_all[4][2][16][40];
    u16* base = &plds_all[wid][0][0][0];
    u16* pw = base + l15 * 40 + grp * 4;              // P write base (row=q=l15)
    const u16* pr = base + l15 * 40 + grp * 8;        // A-frag read base

    const u16* Qw = Qb + (size_t)bg * N * D;
    const u16* Kw = Kb + (size_t)bg * N * D;
    const u16* Vw = VT + (size_t)bg * D * N;

    // Q B-fragments (held whole loop): col=q, k=d
    bfrag qf[2];
#pragma unroll
    for (int qg = 0; qg < 2; ++qg)
        qf[qg] = *reinterpret_cast<const bfrag*>(Qw + (size_t)(qbase + qg * 16 + l15) * D + grp * 8);

    // Wp B-fragments + bias (scalar converts; compiler fuses to cvt_pk)
    bfrag wf[2];
    float bias[2];
#pragma unroll
    for (int oh = 0; oh < 2; ++oh) {
        const float* wrow = Wp + (size_t)(g * D + oh * 16 + l15) * D + grp * 8;
        bfrag w;
#pragma unroll
        for (int e = 0; e < 8; ++e) w[e] = f2bfs(wrow[e]);
        wf[oh] = w;
        bias[oh] = bp[g * D + oh * 16 + l15];
    }

    const f32x4 zf = {0.f, 0.f, 0.f, 0.f};
    f32x4 oacc[2][2];       // [qg][d-half], D[q][d]: row=q, col=d
    float lacc[2] = {0.f, 0.f};
#pragma unroll
    for (int qg = 0; qg < 2; ++qg) { oacc[qg][0] = zf; oacc[qg][1] = zf; }

    const u16* kA = Kw + (size_t)l15 * D + grp * 8;
    const u16* kB = kA + 16 * D;
    const u16* vA = Vw + (size_t)l15 * N + grp * 8;
    const u16* vB = vA + 16 * N;

    bfrag kf0 = *reinterpret_cast<const bfrag*>(kA);
    bfrag kf1 = *reinterpret_cast<const bfrag*>(kB);
    bfrag vf0 = *reinterpret_cast<const bfrag*>(vA);
    bfrag vf1 = *reinterpret_cast<const bfrag*>(vB);

    for (int kb = 0; kb < N; kb += 32) {
        bfrag k0c = kf0, k1c = kf1, v0c = vf0, v1c = vf1;
        if (kb + 32 < N) {                            // register prefetch
            kf0 = *reinterpret_cast<const bfrag*>(kA + (size_t)(kb + 32) * D);
            kf1 = *reinterpret_cast<const bfrag*>(kB + (size_t)(kb + 32) * D);
            vf0 = *reinterpret_cast<const bfrag*>(vA + kb + 32);
            vf1 = *reinterpret_cast<const bfrag*>(vB + kb + 32);
        }

        // S^T = mfma(K, Q): lane holds 4 adjacent keys (rows) for q=l15 (col)
#pragma unroll
        for (int qg = 0; qg < 2; ++qg) {
            f32x4 s0 = __builtin_amdgcn_mfma_f32_16x16x32_bf16(k0c, qf[qg], zf, 0, 0, 0);
            f32x4 s1 = __builtin_amdgcn_mfma_f32_16x16x32_bf16(k1c, qf[qg], zf, 0, 0, 0);
            float e0 = fexp2(s0[0]), e1 = fexp2(s0[1]), e2 = fexp2(s0[2]), e3 = fexp2(s0[3]);
            float e4 = fexp2(s1[0]), e5 = fexp2(s1[1]), e6 = fexp2(s1[2]), e7 = fexp2(s1[3]);
            lacc[qg] += ((e0 + e1) + (e2 + e3)) + ((e4 + e5) + (e6 + e7));
            // keys grp*4+{0..3} and 16+grp*4+{0..3} -> two b64 at row q=l15
            s16x4 w0 = { f2bfs(e0), f2bfs(e1), f2bfs(e2), f2bfs(e3) };
            s16x4 w1 = { f2bfs(e4), f2bfs(e5), f2bfs(e6), f2bfs(e7) };
            *reinterpret_cast<s16x4*>(pw + qg * 640)      = w0;
            *reinterpret_cast<s16x4*>(pw + qg * 640 + 16) = w1;
        }

        // order: all P writes BEFORE the fragment reads
        asm volatile("" ::: "memory");

        // P A-fragments (row=q=l15, k=keys grp*8..+7)
        bfrag pf0 = *reinterpret_cast<const bfrag*>(pr);
        bfrag pf1 = *reinterpret_cast<const bfrag*>(pr + 640);

        // order: reads BEFORE next iteration's writes
        asm volatile("" ::: "memory");

#pragma unroll
        for (int dh = 0; dh < 2; ++dh) {
            oacc[0][dh] = __builtin_amdgcn_mfma_f32_16x16x32_bf16(pf0, dh ? v1c : v0c, oacc[0][dh], 0, 0, 0);
            oacc[1][dh] = __builtin_amdgcn_mfma_f32_16x16x32_bf16(pf1, dh ? v1c : v0c, oacc[1][dh], 0, 0, 0);
        }
    }

    // denominators: lane-local partial, reduce over grp (lanes ^16, ^32)
    float linv[2];
#pragma unroll
    for (int qg = 0; qg < 2; ++qg) {
        float v = lacc[qg];
        v += __shfl_xor(v, 16);
        v += __shfl_xor(v, 32);
        linv[qg] = 1.0f / v;
    }

    // normalize O (rows q=grp*4+r need linv from lane q) and write O tile
#pragma unroll
    for (int qg = 0; qg < 2; ++qg) {
#pragma unroll
        for (int r = 0; r < 4; ++r) {
            const float ir = __shfl(linv[qg], grp * 4 + r);
            u16* po = base + qg * 640 + (grp * 4 + r) * 40 + l15;
#pragma unroll
            for (int dh = 0; dh < 2; ++dh)
                po[dh * 16] = (u16)f2bfs(oacc[qg][dh][r] * ir);
        }
    }

    asm volatile("" ::: "memory");

    bfrag of0 = *reinterpret_cast<const bfrag*>(pr);
    bfrag of1 = *reinterpret_cast<const bfrag*>(pr + 640);

    // out[o][q] = Wp @ O + bp
#pragma unroll
    for (int qg = 0; qg < 2; ++qg) {
#pragma unroll
        for (int oh = 0; oh < 2; ++oh) {
            f32x4 c = {bias[oh], bias[oh], bias[oh], bias[oh]};
            c = __builtin_amdgcn_mfma_f32_16x16x32_bf16(qg ? of1 : of0, wf[oh], c, 0, 0, 0);
            *reinterpret_cast<float4*>(out + (size_t)bg * D * N +
                                       (size_t)(oh * 16 + l15) * N +
                                       qbase + qg * 16 + grp * 4) =
                make_float4(c[0], c[1], c[2], c[3]);
        }
    }
}

extern "C" void kernel_launch(void* const* d_in, const int* in_sizes, int n_in,
                              void* d_out, int out_size, void* d_ws, size_t ws_size,
                              hipStream_t stream) {
    const float* x  = (const float*)d_in[0];
    const float* Wq = (const float*)d_in[1];
    const float* bq = (const float*)d_in[2];
    const float* Wk = (const float*)d_in[3];
    const float* bk = (const float*)d_in[4];
    const float* Wv = (const float*)d_in[5];
    const float* bv = (const float*)d_in[6];
    const float* Wp = (const float*)d_in[7];
    const float* bp = (const float*)d_in[8];
    float* out = (float*)d_out;

    u16* Qb = (u16*)d_ws;                        // [16][4096][32] bf16 = 4 MB
    u16* Kb = Qb + (size_t)NBG * N * D;          // 4 MB
    u16* VT = Kb + (size_t)NBG * N * D;          // [16][32][4096] bf16 = 4 MB

    proj_kernel<<<dim3(N / 256, NBG, 3), 256, 0, stream>>>(x, Wq, bq, Wk, bk, Wv, bv, Qb, Kb, VT);
    attn_kernel<<<dim3(NBG * (N / 128)), 256, 0, stream>>>(Qb, Kb, VT, Wp, bp, out);
}

// Round 7
// 107.441 us; speedup vs baseline: 1.2820x; 1.0003x over previous
//
#include <hip/hip_runtime.h>
#include <hip/hip_bf16.h>

// SelfAttention b=2, heads=8, D=32, n=4096 (64x64).
// Pass 1 (proj_kernel, z=Q/K/V): x -> Q,K bf16 [bg][n][32] (Q pre-scaled by
//   SCALE*log2e), V^T bf16 [bg][32][n].
// Pass 2 (attn_kernel): MFMA flash attention, 4 indep waves/block, 32 q/wave.
//   Swapped QK^T (mfma(K,Q) -> S^T) so 4 adjacent keys are lane-local:
//   exp2 -> packed short4 ds_write_b64. P/O tiles in per-wave LDS, stride
//   80B (bank-uniform). No block barriers. K/V register-prefetched.
// LDS accesses are all short-element typed + explicit compiler memory
// barriers between write->read handoffs (TBAA reorder bug fix, round 3).

constexpr int D = 32;
constexpr int N = 4096;
constexpr int NBG = 16;
constexpr float SCALE = 0.17677669529663687f;   // 32^-0.5
constexpr float LOG2E = 1.4426950408889634f;

using bfrag = __attribute__((ext_vector_type(8))) short;   // 8 bf16
using s16x4 = __attribute__((ext_vector_type(4))) short;
using s16x8 = __attribute__((ext_vector_type(8))) short;
using f32x4 = __attribute__((ext_vector_type(4))) float;
typedef unsigned short u16;
typedef unsigned int u32;

__device__ __forceinline__ float fexp2(float x) { return __builtin_amdgcn_exp2f(x); }

__device__ __forceinline__ short f2bfs(float f) {
    __hip_bfloat16 h = __float2bfloat16(f);
    return (short)__builtin_bit_cast(u16, h);
}

// ---------------- pass 1: projections -> bf16 scratch ----------------
__global__ __launch_bounds__(256) void proj_kernel(
    const float* __restrict__ x,
    const float* __restrict__ Wq, const float* __restrict__ bq,
    const float* __restrict__ Wk, const float* __restrict__ bk,
    const float* __restrict__ Wv, const float* __restrict__ bv,
    u16* __restrict__ Qb, u16* __restrict__ Kb, u16* __restrict__ VT) {
    const int bg = blockIdx.y, g = bg & 7;
    const int z  = blockIdx.z;                       // 0=Q 1=K 2=V
    const int i  = blockIdx.x * 256 + threadIdx.x;

    const float* W  = (z == 0) ? Wq : (z == 1) ? Wk : Wv;
    const float* bb = (z == 0) ? bq : (z == 1) ? bk : bv;

    const float* xb = x + (size_t)bg * D * N;
    float xv[D];
#pragma unroll
    for (int d = 0; d < D; ++d) xv[d] = xb[(size_t)d * N + i];

    const float* w = W + g * D * D;
    float acc[D];
#pragma unroll
    for (int o = 0; o < D; ++o) {
        float a0 = 0.f, a1 = 0.f, a2 = 0.f, a3 = 0.f;
#pragma unroll
        for (int d = 0; d < D; d += 4) {
            a0 = fmaf(w[o * D + d    ], xv[d    ], a0);
            a1 = fmaf(w[o * D + d + 1], xv[d + 1], a1);
            a2 = fmaf(w[o * D + d + 2], xv[d + 2], a2);
            a3 = fmaf(w[o * D + d + 3], xv[d + 3], a3);
        }
        acc[o] = (a0 + a1) + (a2 + a3) + bb[g * D + o];
    }

    if (z == 2) {                                    // V -> transposed [d][n]
        u16* vp = VT + (size_t)bg * D * N + i;
#pragma unroll
        for (int o = 0; o < D; ++o)
            vp[(size_t)o * N] = (u16)f2bfs(acc[o]);
    } else {                                         // Q/K -> row [n][32]
        const float s = (z == 0) ? (SCALE * LOG2E) : 1.0f;
        u16* dst = ((z == 0) ? Qb : Kb) + ((size_t)bg * N + i) * D;
#pragma unroll
        for (int t = 0; t < 4; ++t) {
            s16x8 v;
#pragma unroll
            for (int e = 0; e < 8; ++e) v[e] = f2bfs(acc[8 * t + e] * s);
            *reinterpret_cast<s16x8*>(dst + 8 * t) = v;
        }
    }
}

// ---------------- pass 2: MFMA flash attention ----------------
__global__ __launch_bounds__(256) void attn_kernel(
    const u16* __restrict__ Qb, const u16* __restrict__ Kb, const u16* __restrict__ VT,
    const float* __restrict__ Wp, const float* __restrict__ bp,
    float* __restrict__ out) {
    const int s = blockIdx.x;
    const int bg = s & 15, qt = s >> 4, g = bg & 7;   // bg fastest -> XCD L2 reuse
    const int wid = threadIdx.x >> 6;
    const int lane = threadIdx.x & 63;
    const int l15 = lane & 15, grp = lane >> 4;
    const int qbase = qt * 128 + wid * 32;            // 32 q rows per wave

    // per-wave P/O tile: [2 qg][16 rows][40 u16] (80B stride, bank-uniform)
    __shared__ u16 plds_all[4][2][16][40];
    u16* base = &plds_all[wid][0][0][0];
    u16* pw = base + l15 * 40 + grp * 4;              // P write base (row=q=l15)
    const u16* pr = base + l15 * 40 + grp * 8;        // A-frag read base

    const u16* Qw = Qb + (size_t)bg * N * D;
    const u16* Kw = Kb + (size_t)bg * N * D;
    const u16* Vw = VT + (size_t)bg * D * N;

    // Q B-fragments (held whole loop): col=q, k=d
    bfrag qf[2];
#pragma unroll
    for (int qg = 0; qg < 2; ++qg)
        qf[qg] = *reinterpret_cast<const bfrag*>(Qw + (size_t)(qbase + qg * 16 + l15) * D + grp * 8);

    // Wp B-fragments + bias (scalar converts; compiler fuses to cvt_pk)
    bfrag wf[2];
    float bias[2];
#pragma unroll
    for (int oh = 0; oh < 2; ++oh) {
        const float* wrow = Wp + (size_t)(g * D + oh * 16 + l15) * D + grp * 8;
        bfrag w;
#pragma unroll
        for (int e = 0; e < 8; ++e) w[e] = f2bfs(wrow[e]);
        wf[oh] = w;
        bias[oh] = bp[g * D + oh * 16 + l15];
    }

    const f32x4 zf = {0.f, 0.f, 0.f, 0.f};
    f32x4 oacc[2][2];       // [qg][d-half], D[q][d]: row=q, col=d
    float lacc[2] = {0.f, 0.f};
#pragma unroll
    for (int qg = 0; qg < 2; ++qg) { oacc[qg][0] = zf; oacc[qg][1] = zf; }

    const u16* kA = Kw + (size_t)l15 * D + grp * 8;
    const u16* kB = kA + 16 * D;
    const u16* vA = Vw + (size_t)l15 * N + grp * 8;
    const u16* vB = vA + 16 * N;

    bfrag kf0 = *reinterpret_cast<const bfrag*>(kA);
    bfrag kf1 = *reinterpret_cast<const bfrag*>(kB);
    bfrag vf0 = *reinterpret_cast<const bfrag*>(vA);
    bfrag vf1 = *reinterpret_cast<const bfrag*>(vB);

    for (int kb = 0; kb < N; kb += 32) {
        bfrag k0c = kf0, k1c = kf1, v0c = vf0, v1c = vf1;
        if (kb + 32 < N) {                            // register prefetch
            kf0 = *reinterpret_cast<const bfrag*>(kA + (size_t)(kb + 32) * D);
            kf1 = *reinterpret_cast<const bfrag*>(kB + (size_t)(kb + 32) * D);
            vf0 = *reinterpret_cast<const bfrag*>(vA + kb + 32);
            vf1 = *reinterpret_cast<const bfrag*>(vB + kb + 32);
        }

        // S^T = mfma(K, Q): lane holds 4 adjacent keys (rows) for q=l15 (col)
#pragma unroll
        for (int qg = 0; qg < 2; ++qg) {
            f32x4 s0 = __builtin_amdgcn_mfma_f32_16x16x32_bf16(k0c, qf[qg], zf, 0, 0, 0);
            f32x4 s1 = __builtin_amdgcn_mfma_f32_16x16x32_bf16(k1c, qf[qg], zf, 0, 0, 0);
            float e0 = fexp2(s0[0]), e1 = fexp2(s0[1]), e2 = fexp2(s0[2]), e3 = fexp2(s0[3]);
            float e4 = fexp2(s1[0]), e5 = fexp2(s1[1]), e6 = fexp2(s1[2]), e7 = fexp2(s1[3]);
            lacc[qg] += ((e0 + e1) + (e2 + e3)) + ((e4 + e5) + (e6 + e7));
            // keys grp*4+{0..3} and 16+grp*4+{0..3} -> two b64 at row q=l15
            s16x4 w0 = { f2bfs(e0), f2bfs(e1), f2bfs(e2), f2bfs(e3) };
            s16x4 w1 = { f2bfs(e4), f2bfs(e5), f2bfs(e6), f2bfs(e7) };
            *reinterpret_cast<s16x4*>(pw + qg * 640)      = w0;
            *reinterpret_cast<s16x4*>(pw + qg * 640 + 16) = w1;
        }

        // order: all P writes BEFORE the fragment reads
        asm volatile("" ::: "memory");

        // P A-fragments (row=q=l15, k=keys grp*8..+7)
        bfrag pf0 = *reinterpret_cast<const bfrag*>(pr);
        bfrag pf1 = *reinterpret_cast<const bfrag*>(pr + 640);

        // order: reads BEFORE next iteration's writes
        asm volatile("" ::: "memory");

#pragma unroll
        for (int dh = 0; dh < 2; ++dh) {
            oacc[0][dh] = __builtin_amdgcn_mfma_f32_16x16x32_bf16(pf0, dh ? v1c : v0c, oacc[0][dh], 0, 0, 0);
            oacc[1][dh] = __builtin_amdgcn_mfma_f32_16x16x32_bf16(pf1, dh ? v1c : v0c, oacc[1][dh], 0, 0, 0);
        }
    }

    // denominators: lane-local partial, reduce over grp (lanes ^16, ^32)
    float linv[2];
#pragma unroll
    for (int qg = 0; qg < 2; ++qg) {
        float v = lacc[qg];
        v += __shfl_xor(v, 16);
        v += __shfl_xor(v, 32);
        linv[qg] = 1.0f / v;
    }

    // normalize O (rows q=grp*4+r need linv from lane q) and write O tile
#pragma unroll
    for (int qg = 0; qg < 2; ++qg) {
#pragma unroll
        for (int r = 0; r < 4; ++r) {
            const float ir = __shfl(linv[qg], grp * 4 + r);
            u16* po = base + qg * 640 + (grp * 4 + r) * 40 + l15;
#pragma unroll
            for (int dh = 0; dh < 2; ++dh)
                po[dh * 16] = (u16)f2bfs(oacc[qg][dh][r] * ir);
        }
    }

    asm volatile("" ::: "memory");

    bfrag of0 = *reinterpret_cast<const bfrag*>(pr);
    bfrag of1 = *reinterpret_cast<const bfrag*>(pr + 640);

    // out[o][q] = Wp @ O + bp
#pragma unroll
    for (int qg = 0; qg < 2; ++qg) {
#pragma unroll
        for (int oh = 0; oh < 2; ++oh) {
            f32x4 c = {bias[oh], bias[oh], bias[oh], bias[oh]};
            c = __builtin_amdgcn_mfma_f32_16x16x32_bf16(qg ? of1 : of0, wf[oh], c, 0, 0, 0);
            *reinterpret_cast<float4*>(out + (size_t)bg * D * N +
                                       (size_t)(oh * 16 + l15) * N +
                                       qbase + qg * 16 + grp * 4) =
                make_float4(c[0], c[1], c[2], c[3]);
        }
    }
}

extern "C" void kernel_launch(void* const* d_in, const int* in_sizes, int n_in,
                              void* d_out, int out_size, void* d_ws, size_t ws_size,
                              hipStream_t stream) {
    const float* x  = (const float*)d_in[0];
    const float* Wq = (const float*)d_in[1];
    const float* bq = (const float*)d_in[2];
    const float* Wk = (const float*)d_in[3];
    const float* bk = (const float*)d_in[4];
    const float* Wv = (const float*)d_in[5];
    const float* bv = (const float*)d_in[6];
    const float* Wp = (const float*)d_in[7];
    const float* bp = (const float*)d_in[8];
    float* out = (float*)d_out;

    u16* Qb = (u16*)d_ws;                        // [16][4096][32] bf16 = 4 MB
    u16* Kb = Qb + (size_t)NBG * N * D;          // 4 MB
    u16* VT = Kb + (size_t)NBG * N * D;          // [16][32][4096] bf16 = 4 MB

    proj_kernel<<<dim3(N / 256, NBG, 3), 256, 0, stream>>>(x, Wq, bq, Wk, bk, Wv, bv, Qb, Kb, VT);
    attn_kernel<<<dim3(NBG * (N / 128)), 256, 0, stream>>>(Qb, Kb, VT, Wp, bp, out);
}